// Round 2
// baseline (632.426 us; speedup 1.0000x reference)
//
#include <hip/hip_runtime.h>

// Board: 4096 x 4096 int32 in {0,1,2}  (0=empty, 1=black, 2=white)
// Outputs are BOOLEAN in the reference -> harness stores them as int32 (0/1),
// concatenated flat in d_out in return order:
//   bamboo_black, bamboo_white, tiger_black, tiger_white,
//   empty_triangle_black, empty_triangle_white   -> each (4095,4095)
//   eye_black, eye_white                         -> each (4094,4094)

#define BW   4096
#define W1   4095
#define W2   4094

__global__ __launch_bounds__(256)
void motif_kernel(const int* __restrict__ board, int* __restrict__ out) {
    const int j = blockIdx.x * 256 + threadIdx.x;
    const int i = blockIdx.y;
    if (j >= W1) return;

    const int* row0 = board + i * BW;
    const int* row1 = row0 + BW;

    const int a = row0[j];     // board[i  ][j  ]
    const int b = row0[j + 1]; // board[i  ][j+1]
    const int c = row1[j];     // board[i+1][j  ]
    const int d = row1[j + 1]; // board[i+1][j+1]

    // Per-class corner counts.  diag = {a,d}, anti = {b,c}
    const int nb_d = (a == 1) + (d == 1);
    const int nb_a = (b == 1) + (c == 1);
    const int nw_d = (a == 2) + (d == 2);
    const int nw_a = (b == 2) + (c == 2);
    const int ne_d = (a == 0) + (d == 0);
    const int ne_a = (b == 0) + (c == 0);

    const int nb = nb_d + nb_a;   // black_s2
    const int nw = nw_d + nw_a;   // white_s2
    const int ne = ne_d + ne_a;   // empty_s2

    const bool bamboo_b = ((nb_d == 2) & (ne_a == 2)) | ((nb_a == 2) & (ne_d == 2));
    const bool bamboo_w = ((nw_d == 2) & (ne_a == 2)) | ((nw_a == 2) & (ne_d == 2));
    const bool any_empty = ne >= 1;
    const bool tiger_b = (nb >= 2) & any_empty;
    const bool tiger_w = (nw >= 2) & any_empty;
    const bool et_b = (nb == 3) & (ne == 1);
    const bool et_w = (nw == 3) & (ne == 1);

    const int N1 = W1 * W1;                 // 16,769,025
    const int o  = i * W1 + j;
    out[o]           = (int)bamboo_b;
    out[N1 + o]      = (int)bamboo_w;
    out[2 * N1 + o]  = (int)tiger_b;
    out[3 * N1 + o]  = (int)tiger_w;
    out[4 * N1 + o]  = (int)et_b;
    out[5 * N1 + o]  = (int)et_w;

    // Eyes: output (r,c) in [0,4094)^2, center = board[r+1][c+1] which is `d`
    // for r=i,c=j; cross arms: up=b, left=c, down=board[i+2][j+1],
    // right=board[i+1][j+2].
    if ((i < W2) & (j < W2)) {
        const int dn = board[(i + 2) * BW + (j + 1)];
        const int rt = row1[j + 2];
        const bool eye_b = (d == 0) & (b == 1) & (c == 1) & (dn == 1) & (rt == 1);
        const bool eye_w = (d == 0) & (b == 2) & (c == 2) & (dn == 2) & (rt == 2);
        const int o2 = 6 * N1 + i * W2 + j;
        out[o2]            = (int)eye_b;
        out[o2 + W2 * W2]  = (int)eye_w;
    }
}

extern "C" void kernel_launch(void* const* d_in, const int* in_sizes, int n_in,
                              void* d_out, int out_size, void* d_ws, size_t ws_size,
                              hipStream_t stream) {
    const int* board = (const int*)d_in[0];
    int* out = (int*)d_out;

    dim3 block(256, 1, 1);
    dim3 grid((W1 + 255) / 256, W1, 1);
    motif_kernel<<<grid, block, 0, stream>>>(board, out);
}

// Round 3
// 612.611 us; speedup vs baseline: 1.0323x; 1.0323x over previous
//
#include <hip/hip_runtime.h>

// Board: 4096 x 4096 int32 in {0,1,2}  (0=empty, 1=black, 2=white)
// Outputs are BOOLEAN -> int32 (0/1), concatenated flat in d_out:
//   bamboo_b, bamboo_w, tiger_b, tiger_w, etri_b, etri_w  -> each (4095,4095)
//   eye_b, eye_w                                          -> each (4094,4094)
//
// Layout: 4 columns/thread (16B-aligned int4 board loads), 8-row strip/block
// with a rolling 3-row x 6-col register window (block loads ROWS+2 rows).
// Stores: 16B vector stores at 4-byte alignment (gfx950 global_store_dwordx4
// only needs dword alignment; reduced-alignment vector type below).

#define BW   4096
#define W1   4095
#define W2   4094
#define ROWS 8

typedef int i4u __attribute__((vector_size(16), aligned(4)));   // unaligned store
typedef int i4a __attribute__((vector_size(16), aligned(16)));  // aligned load
typedef int i2a __attribute__((vector_size(8),  aligned(8)));

__global__ __launch_bounds__(256)
void motif_kernel(const int* __restrict__ board, int* __restrict__ out) {
    const int t  = blockIdx.x * 256 + threadIdx.x;  // 0..1023
    const int j0 = t << 2;                          // 0,4,...,4092
    const int i0 = blockIdx.y * ROWS;
    const bool tailj = (j0 == BW - 4);              // last 4-col group

    int c0[6], c1[6], c2[6];                        // rolling row windows

    const int* rp = board + (size_t)i0 * BW + j0;

    auto load6 = [&](const int* p, int* w) {
        i4a v = *(const i4a*)p;                     // 16B aligned (row=16KB, j0%4==0)
        w[0] = v[0]; w[1] = v[1]; w[2] = v[2]; w[3] = v[3];
        if (!tailj) { i2a u = *(const i2a*)(p + 4); w[4] = u[0]; w[5] = u[1]; }
        else        { w[4] = 0; w[5] = 0; }         // cols 4096/4097 don't exist
    };

    load6(rp, c0);          // row i0
    load6(rp + BW, c1);     // row i0+1  (i0 <= 4088 so always in range)

    const int N1 = W1 * W1;
    const int N2 = W2 * W2;

    #pragma unroll
    for (int r = 0; r < ROWS; ++r) {
        const int i = i0 + r;
        if (i >= W1) break;                         // uniform across block
        if (i + 2 < BW)
            load6(board + (size_t)(i + 2) * BW + j0, c2);

        int vb[4], vw[4], vtb[4], vtw[4], veb[4], vew[4], eb[4], ew[4];
        #pragma unroll
        for (int k = 0; k < 4; ++k) {
            const int a = c0[k], b = c0[k + 1], c = c1[k], d = c1[k + 1];
            const int nb_d = (a == 1) + (d == 1), nb_a = (b == 1) + (c == 1);
            const int nw_d = (a == 2) + (d == 2), nw_a = (b == 2) + (c == 2);
            const int ne_d = (a == 0) + (d == 0), ne_a = (b == 0) + (c == 0);
            const int nb = nb_d + nb_a, nw = nw_d + nw_a, ne = ne_d + ne_a;
            vb[k]  = (int)(((nb_d == 2) & (ne_a == 2)) | ((nb_a == 2) & (ne_d == 2)));
            vw[k]  = (int)(((nw_d == 2) & (ne_a == 2)) | ((nw_a == 2) & (ne_d == 2)));
            const int anyE = (int)(ne >= 1);
            vtb[k] = ((int)(nb >= 2)) & anyE;
            vtw[k] = ((int)(nw >= 2)) & anyE;
            veb[k] = (int)((nb == 3) & (ne == 1));
            vew[k] = (int)((nw == 3) & (ne == 1));
            // eye at (i, j0+k): center=c1[k+1], up=b, left=c, down=c2[k+1], right=c1[k+2]
            const int dn = c2[k + 1], rt = c1[k + 2];
            eb[k] = (int)((d == 0) & (b == 1) & (c == 1) & (dn == 1) & (rt == 1));
            ew[k] = (int)((d == 0) & (b == 2) & (c == 2) & (dn == 2) & (rt == 2));
        }

        const int o = i * W1 + j0;
        if (!tailj) {
            i4u s;
            s[0]=vb[0];  s[1]=vb[1];  s[2]=vb[2];  s[3]=vb[3];  *(i4u*)(out + o)          = s;
            s[0]=vw[0];  s[1]=vw[1];  s[2]=vw[2];  s[3]=vw[3];  *(i4u*)(out + o + N1)     = s;
            s[0]=vtb[0]; s[1]=vtb[1]; s[2]=vtb[2]; s[3]=vtb[3]; *(i4u*)(out + o + 2*N1)   = s;
            s[0]=vtw[0]; s[1]=vtw[1]; s[2]=vtw[2]; s[3]=vtw[3]; *(i4u*)(out + o + 3*N1)   = s;
            s[0]=veb[0]; s[1]=veb[1]; s[2]=veb[2]; s[3]=veb[3]; *(i4u*)(out + o + 4*N1)   = s;
            s[0]=vew[0]; s[1]=vew[1]; s[2]=vew[2]; s[3]=vew[3]; *(i4u*)(out + o + 5*N1)   = s;
        } else {
            #pragma unroll
            for (int k = 0; k < 3; ++k) {           // j = 4092..4094 (< W1)
                out[o + k]          = vb[k];
                out[o + k + N1]     = vw[k];
                out[o + k + 2*N1]   = vtb[k];
                out[o + k + 3*N1]   = vtw[k];
                out[o + k + 4*N1]   = veb[k];
                out[o + k + 5*N1]   = vew[k];
            }
        }

        if (i < W2) {
            const int o2 = 6 * N1 + i * W2 + j0;
            if (!tailj) {
                i4u s;
                s[0]=eb[0]; s[1]=eb[1]; s[2]=eb[2]; s[3]=eb[3]; *(i4u*)(out + o2)      = s;
                s[0]=ew[0]; s[1]=ew[1]; s[2]=ew[2]; s[3]=ew[3]; *(i4u*)(out + o2 + N2) = s;
            } else {                                // j = 4092,4093 (< W2)
                out[o2]          = eb[0];
                out[o2 + 1]      = eb[1];
                out[o2 + N2]     = ew[0];
                out[o2 + N2 + 1] = ew[1];
            }
        }

        #pragma unroll
        for (int q = 0; q < 6; ++q) { c0[q] = c1[q]; c1[q] = c2[q]; }
    }
}

extern "C" void kernel_launch(void* const* d_in, const int* in_sizes, int n_in,
                              void* d_out, int out_size, void* d_ws, size_t ws_size,
                              hipStream_t stream) {
    const int* board = (const int*)d_in[0];
    int* out = (int*)d_out;

    dim3 block(256, 1, 1);
    dim3 grid(4, (W1 + ROWS - 1) / ROWS, 1);   // 4 x 512 blocks
    motif_kernel<<<grid, block, 0, stream>>>(board, out);
}